// Round 12
// baseline (22140.985 us; speedup 1.0000x reference)
//
#include <hip/hip_runtime.h>

#define BB    128
#define SEQL  336
#define PREDN 24
#define IN    64
#define HH    256
#define GG    1024          // 4*H
#define KTOT  320           // IN + H
#define NBLK  256
#define NTHR  1024

// ---- static device scratch (~5.5 MB .bss; re-initialized by prep every call) ----
__device__ float g_we[2 * GG * KTOT];    // enc W fp32 [dir][col][k], col=(gate<<8)|n
__device__ float g_wd[2 * GG * KTOT];    // dec W fp32
__device__ float g_bse[2 * GG];          // combined bias, col order
__device__ float g_bsd[2 * GG];
__device__ float g_lwt[2 * HH * IN];     // lin W [k2][o], k2 = dir*256+k
__device__ float g_lb[IN];
__device__ float g_part[BB * 2 * IN];    // head partial y halves
__device__ int   g_flag[BB * 2 * 16];    // per-(b,dir) event counter, 64 B apart

#define N_WT   (2 * GG * KTOT)           // 655360
#define N_PREP (2 * N_WT + 4 * GG + 2 * HH * IN + IN + BB * 2 * IN + BB * 2 * 16)

// Weights -> [dir][col][k] fp32; combine biases (col order); zero part/flags.
__global__ void prep_kernel(const float* __restrict__ eWih,
                            const float* __restrict__ eWhh,
                            const float* __restrict__ ebih,
                            const float* __restrict__ ebhh,
                            const float* __restrict__ dWih,
                            const float* __restrict__ dWhh,
                            const float* __restrict__ dbih,
                            const float* __restrict__ dbhh,
                            const float* __restrict__ linW,
                            const float* __restrict__ linb)
{
    int idx = blockIdx.x * 256 + threadIdx.x;
    if (idx >= N_PREP) return;

    if (idx < N_WT) {                 // enc
        int d   = idx / (GG * KTOT);
        int r   = idx % (GG * KTOT);
        int col = r / KTOT;
        int k   = r % KTOT;
        int g   = col >> 8, n2 = col & 255;
        int j   = g * HH + n2;
        g_we[idx] = (k < IN) ? eWih[(d * GG + j) * IN + k]
                             : eWhh[(d * GG + j) * HH + (k - IN)];
        return;
    }
    idx -= N_WT;
    if (idx < N_WT) {                 // dec
        int d   = idx / (GG * KTOT);
        int r   = idx % (GG * KTOT);
        int col = r / KTOT;
        int k   = r % KTOT;
        int g   = col >> 8, n2 = col & 255;
        int j   = g * HH + n2;
        g_wd[idx] = (k < IN) ? dWih[(d * GG + j) * IN + k]
                             : dWhh[(d * GG + j) * HH + (k - IN)];
        return;
    }
    idx -= N_WT;
    if (idx < 2 * GG) {               // enc bias, col order
        int d = idx / GG, col = idx % GG;
        int j = (col >> 8) * HH + (col & 255);
        g_bse[idx] = ebih[d * GG + j] + ebhh[d * GG + j];
        return;
    }
    idx -= 2 * GG;
    if (idx < 2 * GG) {               // dec bias
        int d = idx / GG, col = idx % GG;
        int j = (col >> 8) * HH + (col & 255);
        g_bsd[idx] = dbih[d * GG + j] + dbhh[d * GG + j];
        return;
    }
    idx -= 2 * GG;
    if (idx < 2 * HH * IN) {          // linWT[k2][o]
        int k = idx / IN, o = idx % IN;
        g_lwt[idx] = linW[o * (2 * HH) + k];
        return;
    }
    idx -= 2 * HH * IN;
    if (idx < IN) { g_lb[idx] = linb[idx]; return; }
    idx -= IN;
    if (idx < BB * 2 * IN) { g_part[idx] = 0.0f; return; }
    idx -= BB * 2 * IN;
    if (idx < BB * 2 * 16) { g_flag[idx] = 0; return; }
}

__device__ __forceinline__ float sigm(float v) { return 1.0f / (1.0f + expf(-v)); }

__device__ __forceinline__ float agent_ld(const float* p) {
    return __hip_atomic_load(p, __ATOMIC_RELAXED, __HIP_MEMORY_SCOPE_AGENT);
}
__device__ __forceinline__ void agent_st(float* p, float v) {
    __hip_atomic_store(p, v, __ATOMIC_RELAXED, __HIP_MEMORY_SCOPE_AGENT);
}

// One block per (dir, batch): 256 blocks x 1024 threads. Thread = one gate-
// column; its 320 fp32 weights live in VGPRs (320 regs; CU file = 2 MB holds
// the full 1.31 MB W). The t-recurrence is block-local: activations (x_t | h)
// in a 320-float LDS buffer (broadcast reads), c in registers of threads
// 0..255, preactivations exchanged via a 4 KB LDS buffer. ZERO inter-block
// traffic except 24 pairwise head events (partial-y swap via sc1 + relaxed
// flags, the round-9/10-proven pattern). Replaces 637 16-block syncs
// (4.8 us/step serial latency) with 24 2-block syncs.
__global__ __launch_bounds__(NTHR, 1)
void lstm_main(const float* __restrict__ x, float* __restrict__ out)
{
    __shared__ __align__(16) float act[KTOT];   // [x_t(64) | h(256)]
    __shared__ float pre[GG];                   // per-col preactivations
    __shared__ float ysl[PREDN * IN];           // local fp32 y history
    __shared__ float lwl[HH * IN];              // this dir's lin W [k][o]

    const int tid = threadIdx.x;
    const int blk = blockIdx.x;
    const int dir = blk >> 7;
    const int b   = blk & 127;

    for (int i = tid; i < HH * IN; i += NTHR) lwl[i] = g_lwt[dir * HH * IN + i];
    if (tid < HH) act[IN + tid] = 0.0f;         // h0 = 0

    float w[KTOT];
    float bias;
    float c = 0.0f;

    {   // load encoder weights into registers (per-thread contiguous float4s)
        const float4* wp = (const float4*)(g_we + (dir * GG + tid) * KTOT);
        #pragma unroll
        for (int i = 0; i < KTOT / 4; ++i) {
            float4 v = wp[i];
            w[4*i] = v.x; w[4*i+1] = v.y; w[4*i+2] = v.z; w[4*i+3] = v.w;
        }
        bias = g_bse[dir * GG + tid];
    }

    auto update_cells = [&]() {                 // fold pre -> (c, h); h into act
        if (tid < HH) {
            float gi = pre[tid], gf = pre[HH + tid], gg = pre[2*HH + tid], go = pre[3*HH + tid];
            c = sigm(gf) * c + sigm(gi) * tanhf(gg);
            act[IN + tid] = sigm(go) * tanhf(c);
        }
    };
    auto gemv = [&]() {                         // pre[col] = bias + act . w
        float a = bias;
        #pragma unroll
        for (int i = 0; i < KTOT / 4; ++i) {
            float4 av = *(const float4*)&act[4 * i];
            a = fmaf(av.x, w[4*i],     a);
            a = fmaf(av.y, w[4*i+1],   a);
            a = fmaf(av.z, w[4*i+2],   a);
            a = fmaf(av.w, w[4*i+3],   a);
        }
        pre[tid] = a;
    };

    // ---------------- encoder: 336 steps, zero global traffic ----------------
    for (int t = 0; t < SEQL; ++t) {
        if (tid >= 256 && tid < 320) {          // stage x_t (wave 4, coalesced)
            int te = dir ? (SEQL - 1 - t) : t;
            act[tid - 256] = x[(b * SEQL + te) * IN + (tid - 256)];
        }
        if (t > 0) update_cells();              // fold previous step's pre
        __syncthreads();
        gemv();
        __syncthreads();
    }
    update_cells();                             // fold t=335 -> encoder finals

    {   // swap to decoder weights (registers only; no LDS hazard)
        const float4* wp = (const float4*)(g_wd + (dir * GG + tid) * KTOT);
        #pragma unroll
        for (int i = 0; i < KTOT / 4; ++i) {
            float4 v = wp[i];
            w[4*i] = v.x; w[4*i+1] = v.y; w[4*i+2] = v.z; w[4*i+3] = v.w;
        }
        bias = g_bsd[dir * GG + tid];
    }

    int  ev = 0;
    int* myflag = &g_flag[(b * 2 + dir) * 16];
    int* pflag  = &g_flag[(b * 2 + (1 - dir)) * 16];

    // ---------------- decoder: 24 iterations ----------------
    for (int t = 0; t < PREDN; ++t) {
        int L = t ? t : 1;
        for (int s = 0; s < L; ++s) {
            if (tid >= 256 && tid < 320) {      // stage input
                int o = tid - 256;
                if (t == 0) act[o] = x[(b * SEQL + (SEQL - 1)) * IN + o];
                else        { int e = dir ? (L - 1 - s) : s; act[o] = ysl[e * IN + o]; }
            }
            if (s > 0) update_cells();
            __syncthreads();
            gemv();
            __syncthreads();
        }
        update_cells();                         // h after final sub-step
        __syncthreads();

        // head: partial y for this dir, then pairwise exchange
        float pl = 0.0f;
        if (tid < IN) {
            #pragma unroll 8
            for (int k = 0; k < HH; ++k) pl = fmaf(act[IN + k], lwl[k * IN + tid], pl);
            agent_st(&g_part[(b * 2 + dir) * IN + tid], pl);
        }
        ++ev;
        __atomic_signal_fence(__ATOMIC_SEQ_CST);
        __builtin_amdgcn_s_waitcnt(0);          // drain sc1 partial stores
        __atomic_signal_fence(__ATOMIC_SEQ_CST);
        __syncthreads();
        if (tid == 0) {
            __hip_atomic_store(myflag, ev, __ATOMIC_RELAXED, __HIP_MEMORY_SCOPE_AGENT);
            while (__hip_atomic_load(pflag, __ATOMIC_RELAXED, __HIP_MEMORY_SCOPE_AGENT) < ev)
                __builtin_amdgcn_s_sleep(1);
        }
        __syncthreads();
        if (tid < IN) {
            float q = agent_ld(&g_part[(b * 2 + (1 - dir)) * IN + tid]);
            float y = pl + q + g_lb[tid];
            ysl[t * IN + tid] = y;
            if (dir == 0) out[(b * PREDN + t) * IN + tid] = y;
        }
        __syncthreads();                        // ysl visible to stagers
    }
}

extern "C" void kernel_launch(void* const* d_in, const int* in_sizes, int n_in,
                              void* d_out, int out_size, void* d_ws, size_t ws_size,
                              hipStream_t stream)
{
    (void)in_sizes; (void)n_in; (void)out_size; (void)d_ws; (void)ws_size;
    const float* x    = (const float*)d_in[0];
    const float* eWih = (const float*)d_in[1];
    const float* eWhh = (const float*)d_in[2];
    const float* ebih = (const float*)d_in[3];
    const float* ebhh = (const float*)d_in[4];
    const float* dWih = (const float*)d_in[5];
    const float* dWhh = (const float*)d_in[6];
    const float* dbih = (const float*)d_in[7];
    const float* dbhh = (const float*)d_in[8];
    const float* linW = (const float*)d_in[9];
    const float* linb = (const float*)d_in[10];
    float* out = (float*)d_out;

    int prep_blocks = (N_PREP + 255) / 256;
    hipLaunchKernelGGL(prep_kernel, dim3(prep_blocks), dim3(256), 0, stream,
                       eWih, eWhh, ebih, ebhh, dWih, dWhh, dbih, dbhh, linW, linb);

    void* args[] = { (void*)&x, (void*)&out };
    (void)hipLaunchCooperativeKernel((void*)lstm_main, dim3(NBLK), dim3(NTHR), args, 0, stream);
}